// Round 12
// baseline (77.609 us; speedup 1.0000x reference)
//
#include <hip/hip_runtime.h>

typedef unsigned short u16;
typedef __attribute__((ext_vector_type(8))) short bf16x8;
typedef __attribute__((ext_vector_type(4))) float f32x4;
typedef __attribute__((ext_vector_type(8))) float f32x8;
typedef __attribute__((ext_vector_type(16))) float f32x16;
typedef __attribute__((ext_vector_type(4))) unsigned u32x4;
typedef __attribute__((ext_vector_type(2))) int i32x2;

struct alignas(8) u16x4 { u16 x, y, z, w; };

#define MFMA16(A, B, C) __builtin_amdgcn_mfma_f32_16x16x32_bf16(A, B, C, 0, 0, 0)
#define MFMA32(A, B, C) __builtin_amdgcn_mfma_f32_32x32x16_bf16(A, B, C, 0, 0, 0)
// SCALE * log2(e): softmax computed in exp2 domain
#define QSCALE (0.17677669529663689f * 1.4426950408889634f)

__device__ __forceinline__ u16 f2bf(float f) {
  unsigned u = __float_as_uint(f);
  u = (u + 0x7fffu + ((u >> 16) & 1u)) >> 16;
  return (u16)u;
}

__device__ __forceinline__ bf16x8 ldb8(const u16* p) {
  return *reinterpret_cast<const bf16x8*>(p);
}

// async global->LDS, 16B per lane; LDS dest = uniform base + lane*16
__device__ __forceinline__ void glds16(const u16* g, u16* l) {
  __builtin_amdgcn_global_load_lds(
      (const __attribute__((address_space(1))) void*)g,
      (__attribute__((address_space(3))) void*)l, 16, 0, 0);
}

// ---------------------------------------------------------------- prep
__global__ __launch_bounds__(256) void prep_kernel(
    const float* __restrict__ x, const float* __restrict__ akv,
    const float* __restrict__ qw, const float* __restrict__ kvw,
    const float* __restrict__ Wq, const float* __restrict__ Wk,
    const float* __restrict__ Wv, const float* __restrict__ Wp,
    u16* __restrict__ xpT, u16* __restrict__ w2,
    u16* __restrict__ wqs, u16* __restrict__ wks,
    u16* __restrict__ wvs, u16* __restrict__ wps)
{
  __shared__ float sm[64 * 65];
  const int b = blockIdx.x, t = threadIdx.x;
  if (b < 512) {
    const int z = b >> 8, rem = b & 255;
    const int cib = (rem >> 6) * 64, y = rem & 63;
    const float* in = (z ? akv : x);
    const int tc = t & 63, tr = t >> 6;
    #pragma unroll
    for (int i = 0; i < 16; ++i) {
      const int ci = i * 4 + tr;
      sm[ci * 65 + tc] = in[(size_t)(cib + ci) * 4096 + y * 64 + tc];
    }
    __syncthreads();
    u16* dst = xpT + (size_t)z * 4356 * 256;
    #pragma unroll
    for (int i = 0; i < 16; ++i) {
      const int px = i * 4 + tr;
      dst[(size_t)((y + 1) * 66 + px + 1) * 256 + cib + tc] = f2bf(sm[tc * 65 + px]);
    }
    return;
  }
  if (b < 642) {
    const int slot = (b - 512) * 4 + (t >> 6);
    const int z = slot >= 260 ? 1 : 0;
    const int j = slot - z * 260;
    int pos;
    if (j < 66) pos = j;
    else if (j < 132) pos = 65 * 66 + (j - 66);
    else { const int j2 = j - 132; pos = (1 + (j2 >> 1)) * 66 + (j2 & 1) * 65; }
    u16x4 zr = {0, 0, 0, 0};
    *reinterpret_cast<u16x4*>(xpT + (size_t)z * 4356 * 256 + (size_t)pos * 256 + (t & 63) * 4) = zr;
    return;
  }
  if (b < 1154) {
    const int idx = b - 642;
    const int z = idx >> 8, co = idx & 255;
    const float* src = (z ? kvw : qw) + (size_t)co * 2304;
    u16* dst = w2 + (size_t)z * 256 * 2304 + (size_t)co * 2304;
    #pragma unroll
    for (int i = 0; i < 9; ++i) sm[i * 256 + t] = src[i * 256 + t];
    __syncthreads();
    #pragma unroll
    for (int i = 0; i < 9; ++i) dst[i * 256 + t] = f2bf(sm[t * 9 + i]);
    return;
  }
  {
    int idx = (b - 1154) * 256 + t;
    if (idx < 32768) { wqs[idx] = f2bf(Wq[idx] * QSCALE); return; }
    idx -= 32768;
    if (idx < 32768) { wks[idx] = f2bf(Wk[idx]); return; }
    idx -= 32768;
    if (idx < 65536) { wvs[idx] = f2bf(Wv[idx]); return; }
    idx -= 65536;
    wps[idx] = f2bf(Wp[idx]);
  }
}

// ---------------------------------------------------------------- conv3x3
// LDS-staged GEMM, triple-buffered with counted vmcnt(4) (T3/T4),
// T2 swizzle via pre-swizzled global source + swizzled ds_read.
__global__ __launch_bounds__(256, 2) void conv_kernel(
    const u16* __restrict__ xpT, const u16* __restrict__ w2,
    const float* __restrict__ qb, const float* __restrict__ kvb,
    u16* __restrict__ xqt, u16* __restrict__ kvt)
{
  __shared__ u16 ab[3][64 * 64];
  __shared__ u16 bb[3][64 * 64];

  const int z = blockIdx.z;
  const u16* __restrict__ X = xpT + (size_t)z * 4356 * 256;
  const u16* __restrict__ W = w2 + (size_t)z * 256 * 2304;
  const float* bias = z ? kvb : qb;
  u16* out = z ? kvt : xqt;

  const int lane = threadIdx.x & 63, w = threadIdx.x >> 6;
  const int lo = lane & 15, g = lane >> 4;
  const int r8 = lane >> 3, c = lane & 7;
  const int wr = w >> 1, wc = w & 1;
  const int cobase = blockIdx.x * 64;
  const int tbase = blockIdx.y * 64;

  const bool isA = (w < 2);
  const u16* gb[4];
  int ldso[4];
  #pragma unroll
  for (int q = 0; q < 4; ++q) {
    const int flat = w * 4 + q;
    if (flat < 8) {
      const int j = flat;
      gb[q] = W + (size_t)(cobase + j * 8 + r8) * 2304 + (c ^ r8) * 8;
      ldso[q] = j * 512;
    } else {
      const int j = flat - 8;
      const int tok = tbase + j * 8 + r8;
      const int padrow = ((tok >> 6) + 1) * 66 + (tok & 63) + 1;
      gb[q] = X + (size_t)padrow * 256 + (c ^ r8) * 8;
      ldso[q] = j * 512;
    }
  }

  f32x4 acc[2][2] = {};

  auto stage = [&](int s, int bsel) {
    int srcoff;
    if (isA) {
      srcoff = s * 64;
    } else {
      const int kk = s >> 2;
      const int koff = (kk / 3 - 1) * 66 + (kk % 3) - 1;
      srcoff = koff * 256 + (s & 3) * 64;
    }
    u16* lb = isA ? ab[bsel] : bb[bsel];
    #pragma unroll
    for (int q = 0; q < 4; ++q)
      glds16(gb[q] + srcoff, lb + ldso[q]);
  };

  stage(0, 0);
  stage(1, 1);
  asm volatile("s_waitcnt vmcnt(4)" ::: "memory");  // buf0 done; buf1 in flight
  __syncthreads();

  #pragma unroll 1
  for (int s = 0; s < 36; ++s) {
    const int cur = s % 3;
    if (s + 2 < 36) stage(s + 2, (s + 2) % 3);
    #pragma unroll
    for (int ks = 0; ks < 2; ++ks) {
      const int swz = ((ks * 4 + g) ^ (lo & 7)) * 8;
      const int rowA = wr * 32 + lo, colB = wc * 32 + lo;
      bf16x8 a0 = *reinterpret_cast<const bf16x8*>(&ab[cur][rowA * 64 + swz]);
      bf16x8 a1 = *reinterpret_cast<const bf16x8*>(&ab[cur][(rowA + 16) * 64 + swz]);
      bf16x8 b0 = *reinterpret_cast<const bf16x8*>(&bb[cur][colB * 64 + swz]);
      bf16x8 b1 = *reinterpret_cast<const bf16x8*>(&bb[cur][(colB + 16) * 64 + swz]);
      acc[0][0] = MFMA16(a0, b0, acc[0][0]);
      acc[0][1] = MFMA16(a0, b1, acc[0][1]);
      acc[1][0] = MFMA16(a1, b0, acc[1][0]);
      acc[1][1] = MFMA16(a1, b1, acc[1][1]);
    }
    if (s < 35) {
      if (s + 2 < 36) asm volatile("s_waitcnt vmcnt(4)" ::: "memory");
      else            asm volatile("s_waitcnt vmcnt(0)" ::: "memory");
      __syncthreads();
    }
  }

  #pragma unroll
  for (int af = 0; af < 2; ++af) {
    const int cb = cobase + wr * 32 + af * 16 + 4 * g;
    const float4 bi = *reinterpret_cast<const float4*>(bias + cb);
    #pragma unroll
    for (int bf = 0; bf < 2; ++bf) {
      const int t = tbase + wc * 32 + bf * 16 + lo;
      f32x4 v = acc[af][bf];
      u16x4 pk = { f2bf(v[0] + bi.x), f2bf(v[1] + bi.y),
                   f2bf(v[2] + bi.z), f2bf(v[3] + bi.w) };
      *reinterpret_cast<u16x4*>(out + (size_t)t * 256 + cb) = pk;
    }
  }
}

// ---------------------------------------------------------------- q/k/v proj (merged)
// grid (4, 64, 2): z=0 -> q (x<2) / k (x>=2), out [h][n][16];
//                  z=1 -> v, out in PRE-FRAGMENTED layout Vp.
// Depth-1 register prefetch on all fragment streams.
__global__ __launch_bounds__(256) void qkv_kernel(
    const u16* __restrict__ xqt, const u16* __restrict__ kvt,
    const u16* __restrict__ wqs, const u16* __restrict__ wks,
    const u16* __restrict__ wvs,
    const float* __restrict__ bq, const float* __restrict__ bk,
    const float* __restrict__ bv,
    u16* __restrict__ Qh, u16* __restrict__ Kh, u16* __restrict__ Vp)
{
  const int lane = threadIdx.x & 63, wid = threadIdx.x >> 6;
  const int lo = lane & 15, g = lane >> 4;
  const int bx = blockIdx.x;

  if (blockIdx.z == 0) {
    const bool isq = bx < 2;
    const u16* A = isq ? wqs : wks;
    const u16* Bm = isq ? xqt : kvt;
    const float* bias = isq ? bq : bk;
    const float bsc = isq ? (float)QSCALE : 1.f;
    u16* outp = isq ? Qh : Kh;
    const int c0 = (bx & 1) * 64 + (wid >> 1) * 32;
    const int n0 = blockIdx.y * 64 + (wid & 1) * 32;

    const u16* Ar0 = A + (c0 + lo) * 256 + 8 * g;
    const u16* Ar1 = A + (c0 + 16 + lo) * 256 + 8 * g;
    const u16* Br0 = Bm + (n0 + lo) * 256 + 8 * g;
    const u16* Br1 = Bm + (n0 + 16 + lo) * 256 + 8 * g;

    f32x4 acc[2][2] = {};
    bf16x8 A0 = ldb8(Ar0), A1 = ldb8(Ar1), B0 = ldb8(Br0), B1 = ldb8(Br1);
    #pragma unroll
    for (int s = 0; s < 8; ++s) {
      bf16x8 A0n, A1n, B0n, B1n;
      if (s < 7) {
        const int kn = (s + 1) * 32;
        A0n = ldb8(Ar0 + kn); A1n = ldb8(Ar1 + kn);
        B0n = ldb8(Br0 + kn); B1n = ldb8(Br1 + kn);
      }
      acc[0][0] = MFMA16(A0, B0, acc[0][0]);
      acc[0][1] = MFMA16(A0, B1, acc[0][1]);
      acc[1][0] = MFMA16(A1, B0, acc[1][0]);
      acc[1][1] = MFMA16(A1, B1, acc[1][1]);
      A0 = A0n; A1 = A1n; B0 = B0n; B1 = B1n;
    }
    #pragma unroll
    for (int af = 0; af < 2; ++af) {
      const int cb = c0 + af * 16 + 4 * g;
      const int h = cb >> 4, dd = cb & 15;
      const float4 bi = *reinterpret_cast<const float4*>(bias + cb);
      #pragma unroll
      for (int bfr = 0; bfr < 2; ++bfr) {
        const int n = n0 + bfr * 16 + lo;
        f32x4 v = acc[af][bfr];
        u16x4 pk = { f2bf(v[0] + bi.x * bsc), f2bf(v[1] + bi.y * bsc),
                     f2bf(v[2] + bi.z * bsc), f2bf(v[3] + bi.w * bsc) };
        *reinterpret_cast<u16x4*>(outp + h * 65536 + n * 16 + dd) = pk;
      }
    }
  } else {
    const int n0 = blockIdx.y * 64 + (wid >> 1) * 32;
    const int c0 = bx * 64 + (wid & 1) * 32;

    const u16* Ar0 = kvt + (n0 + lo) * 256 + 8 * g;
    const u16* Ar1 = kvt + (n0 + 16 + lo) * 256 + 8 * g;
    const u16* Br0 = wvs + (c0 + lo) * 256 + 8 * g;
    const u16* Br1 = wvs + (c0 + 16 + lo) * 256 + 8 * g;

    f32x4 acc[2][2] = {};
    bf16x8 A0 = ldb8(Ar0), A1 = ldb8(Ar1), B0 = ldb8(Br0), B1 = ldb8(Br1);
    #pragma unroll
    for (int s = 0; s < 8; ++s) {
      bf16x8 A0n, A1n, B0n, B1n;
      if (s < 7) {
        const int kn = (s + 1) * 32;
        A0n = ldb8(Ar0 + kn); A1n = ldb8(Ar1 + kn);
        B0n = ldb8(Br0 + kn); B1n = ldb8(Br1 + kn);
      }
      acc[0][0] = MFMA16(A0, B0, acc[0][0]);
      acc[0][1] = MFMA16(A0, B1, acc[0][1]);
      acc[1][0] = MFMA16(A1, B0, acc[1][0]);
      acc[1][1] = MFMA16(A1, B1, acc[1][1]);
      A0 = A0n; A1 = A1n; B0 = B0n; B1 = B1n;
    }
    #pragma unroll
    for (int af = 0; af < 2; ++af) {
      const int nb = n0 + af * 16 + 4 * g;
      const int tblk = nb >> 4, hhalf = (nb >> 3) & 1, j0 = nb & 7;
      #pragma unroll
      for (int bfr = 0; bfr < 2; ++bfr) {
        const int cc = c0 + bfr * 16 + lo;
        const int h = cc >> 5, dv = cc & 31;
        const float bi = bv[cc];
        f32x4 v = acc[af][bfr];
        u16x4 pk = { f2bf(v[0] + bi), f2bf(v[1] + bi),
                     f2bf(v[2] + bi), f2bf(v[3] + bi) };
        *reinterpret_cast<u16x4*>(
            Vp + (size_t)h * 131072 + tblk * 512 + hhalf * 256 + dv * 8 + j0) = pk;
      }
    }
  }
}

// ---------------------------------------------------------------- attention
// R12 change (isolated): KV-SPLIT x2 -> grid 1024 blocks (half = bx>>9),
// each block does 2048 kv (8 steps/wave). Blocks write UNNORMALIZED f32
// O-partials + L-partials (linear combine is exact: no max tracking);
// oproj fuses combine+normalize. Prefetch dropped (noise; saves ~26 VGPR ->
// occupancy rises: grid-limit 4/SIMD -> VGPR-limit ~5.5-6/SIMD).
// grid (1024), block 512.
__global__ __launch_bounds__(512, 4) void attn_kernel(
    const u16* __restrict__ Qh, const u16* __restrict__ Kh,
    const u16* __restrict__ Vp, float* __restrict__ Of,
    float* __restrict__ Lf)
{
  __shared__ float olds[16][8][64];
  __shared__ float l_ldsA[8][32], l_ldsB[8][32];

  const int lane = threadIdx.x & 63, w = threadIdx.x >> 6;  // w in [0,8)
  const int lo = lane & 31, hi = lane >> 5;
  const int bx = blockIdx.x;
  const int h = bx & 7;                 // XCD i <- head i (round-robin dispatch)
  const int qg = (bx >> 3) & 63;
  const int half = bx >> 9;
  const int qt0 = qg * 64;

  const u16* Q = Qh + h * 65536;
  const u16* K = Kh + h * 65536;

  const bf16x8 qbA = ldb8(Q + (qt0 + lo) * 16 + 8 * hi);
  const bf16x8 qbB = ldb8(Q + (qt0 + 32 + lo) * 16 + 8 * hi);

  f32x16 oA = {0,0,0,0,0,0,0,0,0,0,0,0,0,0,0,0};
  f32x16 oB = {0,0,0,0,0,0,0,0,0,0,0,0,0,0,0,0};
  float lA0 = 0.f, lA1 = 0.f, lB0 = 0.f, lB1 = 0.f;
  const int kvbase = half * 2048 + w * 256;

  const u16* kptr = K + (kvbase + lo) * 16 + 8 * hi;
  const u16* vptr = Vp + (size_t)h * 131072 + (size_t)kvbase * 32 + lane * 8;

  #pragma unroll 1
  for (int st = 0; st < 8; ++st) {
    const bf16x8 kb = ldb8(kptr);
    const bf16x8 vb0 = ldb8(vptr);
    const bf16x8 vb1 = ldb8(vptr + 512);
    kptr += 512; vptr += 1024;

    const f32x16 zf = {0,0,0,0,0,0,0,0,0,0,0,0,0,0,0,0};
    f32x16 sA = MFMA32(kb, qbA, zf);
    f32x16 sB = MFMA32(kb, qbB, zf);

    // ---- tile A softmax+PV ----
    {
      unsigned cpk[8];
      #pragma unroll
      for (int r = 0; r < 16; r += 2) {
        const float p0 = __builtin_amdgcn_exp2f(sA[r]);
        const float p1 = __builtin_amdgcn_exp2f(sA[r + 1]);
        lA0 += p0; lA1 += p1;
        asm("v_cvt_pk_bf16_f32 %0, %1, %2" : "=v"(cpk[r >> 1]) : "v"(p0), "v"(p1));
      }
      u32x4 fa0, fa1;
      { i32x2 r2 = __builtin_amdgcn_permlane32_swap((int)cpk[0], (int)cpk[2], false, false);
        fa0[0] = (unsigned)r2[0]; fa0[2] = (unsigned)r2[1]; }
      { i32x2 r2 = __builtin_amdgcn_permlane32_swap((int)cpk[1], (int)cpk[3], false, false);
        fa0[1] = (unsigned)r2[0]; fa0[3] = (unsigned)r2[1]; }
      { i32x2 r2 = __builtin_amdgcn_permlane32_swap((int)cpk[4], (int)cpk[6], false, false);
        fa1[0] = (unsigned)r2[0]; fa1[2] = (unsigned)r2[1]; }
      { i32x2 r2 = __builtin_amdgcn_permlane32_swap((int)cpk[5], (int)cpk[7], false, false);
        fa1[1] = (unsigned)r2[0]; fa1[3] = (unsigned)r2[1]; }
      oA = MFMA32(__builtin_bit_cast(bf16x8, fa0), vb0, oA);
      oA = MFMA32(__builtin_bit_cast(bf16x8, fa1), vb1, oA);
    }
    // ---- tile B softmax+PV ----
    {
      unsigned cpk[8];
      #pragma unroll
      for (int r = 0; r < 16; r += 2) {
        const float p0 = __builtin_amdgcn_exp2f(sB[r]);
        const float p1 = __builtin_amdgcn_exp2f(sB[r + 1]);
        lB0 += p0; lB1 += p1;
        asm("v_cvt_pk_bf16_f32 %0, %1, %2" : "=v"(cpk[r >> 1]) : "v"(p0), "v"(p1));
      }
      u32x4 fa0, fa1;
      { i32x2 r2 = __builtin_amdgcn_permlane32_swap((int)cpk[0], (int)cpk[2], false, false);
        fa0[0] = (unsigned)r2[0]; fa0[2] = (unsigned)r2[1]; }
      { i32x2 r2 = __builtin_amdgcn_permlane32_swap((int)cpk[1], (int)cpk[3], false, false);
        fa0[1] = (unsigned)r2[0]; fa0[3] = (unsigned)r2[1]; }
      { i32x2 r2 = __builtin_amdgcn_permlane32_swap((int)cpk[4], (int)cpk[6], false, false);
        fa1[0] = (unsigned)r2[0]; fa1[2] = (unsigned)r2[1]; }
      { i32x2 r2 = __builtin_amdgcn_permlane32_swap((int)cpk[5], (int)cpk[7], false, false);
        fa1[1] = (unsigned)r2[0]; fa1[3] = (unsigned)r2[1]; }
      oB = MFMA32(__builtin_bit_cast(bf16x8, fa0), vb0, oB);
      oB = MFMA32(__builtin_bit_cast(bf16x8, fa1), vb1, oB);
    }
  }

  // ---- cross-wave combine (per block); write UNNORMALIZED partials ----
  float lA = lA0 + lA1;  lA += __shfl_xor(lA, 32);
  float lB = lB0 + lB1;  lB += __shfl_xor(lB, 32);
  if (lane < 32) { l_ldsA[w][lane] = lA; l_ldsB[w][lane] = lB; }

  float* Ofh = Of + (size_t)half * 4096 * 256;
  float* Lfh = Lf + half * 32768 + h * 4096;

  #pragma unroll
  for (int r = 0; r < 16; ++r) olds[r][w][lane] = oA[r];
  __syncthreads();

  if (w == 0 && lane < 32) {
    float L = 0.f;
    #pragma unroll
    for (int w2 = 0; w2 < 8; ++w2) L += l_ldsA[w2][lane];
    Lfh[qt0 + lane] = L;
  }
  if (w == 1 && lane < 32) {
    float L = 0.f;
    #pragma unroll
    for (int w2 = 0; w2 < 8; ++w2) L += l_ldsB[w2][lane];
    Lfh[qt0 + 32 + lane] = L;
  }

  #pragma unroll
  for (int j = 0; j < 2; ++j) {
    const int r = 2 * w + j;
    const int q = (r & 3) + 8 * (r >> 2) + 4 * hi;
    float acc = 0.f;
    #pragma unroll
    for (int w2 = 0; w2 < 8; ++w2) acc += olds[r][w2][lane];
    const int n = qt0 + q;
    Ofh[(size_t)((h << 9) + (n >> 3)) * 256 + ((n & 7) << 5) + lo] = acc;
  }
  __syncthreads();

  #pragma unroll
  for (int r = 0; r < 16; ++r) olds[r][w][lane] = oB[r];
  __syncthreads();

  #pragma unroll
  for (int j = 0; j < 2; ++j) {
    const int r = 2 * w + j;
    const int q = (r & 3) + 8 * (r >> 2) + 4 * hi;
    float acc = 0.f;
    #pragma unroll
    for (int w2 = 0; w2 < 8; ++w2) acc += olds[r][w2][lane];
    const int n = qt0 + 32 + q;
    Ofh[(size_t)((h << 9) + (n >> 3)) * 256 + ((n & 7) << 5) + lo] = acc;
  }
}

// ---------------------------------------------------------------- out proj
// R7-verified tile (64n x 64c, 2x2 acc/wave, grid (64,4)) + fused KV-split
// combine: A-fragment = f2bf((o1+o2) * 1/(L1+L2)). All 8 fragment elements
// share one token q (slot = k0>>5 is constant across the octet).
__global__ __launch_bounds__(256) void oproj_kernel(
    const float* __restrict__ Of, const float* __restrict__ Lf,
    const u16* __restrict__ wps, const float* __restrict__ bp,
    float* __restrict__ outp)
{
  const int lane = threadIdx.x & 63, wid = threadIdx.x >> 6;
  const int lo = lane & 15, g = lane >> 4;
  const int n0 = blockIdx.x * 64 + (wid >> 1) * 32;
  const int c0 = blockIdx.y * 64 + (wid & 1) * 32;

  const float* O1 = Of;
  const float* O2f = Of + (size_t)4096 * 256;
  const float* L1 = Lf;
  const float* L2 = Lf + 32768;

  f32x4 acc[2][2] = {};
  #pragma unroll
  for (int s = 0; s < 8; ++s) {
    const int k0 = s * 32 + 8 * g;

    bf16x8 Afr[2];
    #pragma unroll
    for (int af = 0; af < 2; ++af) {
      const int row = n0 + af * 16 + lo;
      const size_t off = (size_t)row * 256 + k0;
      const f32x8 a = *reinterpret_cast<const f32x8*>(O1 + off);
      const f32x8 b = *reinterpret_cast<const f32x8*>(O2f + off);
      const int li = (row >> 9) * 4096 + ((row & 511) << 3) + s;
      const float inv = 1.0f / (L1[li] + L2[li]);
      union { bf16x8 v; u16 e[8]; } rr;
      #pragma unroll
      for (int j = 0; j < 8; ++j) rr.e[j] = f2bf((a[j] + b[j]) * inv);
      Afr[af] = rr.v;
    }
    bf16x8 B0 = ldb8(wps + (c0 + lo) * 256 + k0);
    bf16x8 B1 = ldb8(wps + (c0 + 16 + lo) * 256 + k0);
    acc[0][0] = MFMA16(Afr[0], B0, acc[0][0]);
    acc[0][1] = MFMA16(Afr[0], B1, acc[0][1]);
    acc[1][0] = MFMA16(Afr[1], B0, acc[1][0]);
    acc[1][1] = MFMA16(Afr[1], B1, acc[1][1]);
  }
  #pragma unroll
  for (int af = 0; af < 2; ++af) {
    const int nb = n0 + af * 16 + 4 * g;
    #pragma unroll
    for (int bfr = 0; bfr < 2; ++bfr) {
      const int c = c0 + bfr * 16 + lo;
      const float bi = bp[c];
      f32x4 v = acc[af][bfr];
      float4 r4;
      r4.x = v[0] + bi; r4.y = v[1] + bi; r4.z = v[2] + bi; r4.w = v[3] + bi;
      *reinterpret_cast<float4*>(outp + (size_t)c * 4096 + nb) = r4;
    }
  }
}

// ---------------------------------------------------------------- launch
extern "C" void kernel_launch(void* const* d_in, const int* in_sizes, int n_in,
                              void* d_out, int out_size, void* d_ws, size_t ws_size,
                              hipStream_t stream) {
  (void)in_sizes; (void)n_in; (void)out_size; (void)ws_size;
  const float* x   = (const float*)d_in[0];
  const float* akv = (const float*)d_in[1];
  const float* qw  = (const float*)d_in[2];
  const float* qb  = (const float*)d_in[3];
  const float* kvw = (const float*)d_in[4];
  const float* kvb = (const float*)d_in[5];
  const float* Wq  = (const float*)d_in[6];
  const float* bq  = (const float*)d_in[7];
  const float* Wk  = (const float*)d_in[8];
  const float* bk  = (const float*)d_in[9];
  const float* Wv  = (const float*)d_in[10];
  const float* bv  = (const float*)d_in[11];
  const float* Wp  = (const float*)d_in[12];
  const float* bp  = (const float*)d_in[13];
  float* outp = (float*)d_out;

  char* wsb = (char*)d_ws;
  size_t off = 0;
  auto take = [&](size_t bytes) {
    char* p = wsb + off;
    off = (off + bytes + 255) & ~(size_t)255;
    return p;
  };
  u16* xpT = (u16*)take(2ULL * 4356 * 256 * 2);
  u16* w2  = (u16*)take(2ULL * 256 * 2304 * 2);
  u16* wqs = (u16*)take(128ULL * 256 * 2);
  u16* wks = (u16*)take(128ULL * 256 * 2);
  u16* wvs = (u16*)take(256ULL * 256 * 2);
  u16* wps = (u16*)take(256ULL * 256 * 2);
  u16* xqt = (u16*)take(4096ULL * 256 * 2);
  u16* kvt = (u16*)take(4096ULL * 256 * 2);
  u16* Qh  = (u16*)take(8ULL * 4096 * 16 * 2);
  u16* Kh  = (u16*)take(8ULL * 4096 * 16 * 2);
  u16* Vp  = (u16*)take(8ULL * 131072 * 2);
  float* Of = (float*)take(2ULL * 4096 * 256 * 4);
  float* Lf = (float*)take(2ULL * 8 * 4096 * 4);

  prep_kernel<<<dim3(1922), dim3(256), 0, stream>>>(
      x, akv, qw, kvw, Wq, Wk, Wv, Wp, xpT, w2, wqs, wks, wvs, wps);
  conv_kernel<<<dim3(4, 64, 2), dim3(256), 0, stream>>>(xpT, w2, qb, kvb, xqt, kvt);
  qkv_kernel<<<dim3(4, 64, 2), dim3(256), 0, stream>>>(
      xqt, kvt, wqs, wks, wvs, bq, bk, bv, Qh, Kh, Vp);
  attn_kernel<<<dim3(1024), dim3(512), 0, stream>>>(Qh, Kh, Vp, Of, Lf);
  oproj_kernel<<<dim3(64, 4), dim3(256), 0, stream>>>(Of, Lf, wps, bp, outp);
}

// Round 14
// 69.403 us; speedup vs baseline: 1.1182x; 1.1182x over previous
//
#include <hip/hip_runtime.h>

typedef unsigned short u16;
typedef __attribute__((ext_vector_type(8))) short bf16x8;
typedef __attribute__((ext_vector_type(4))) float f32x4;
typedef __attribute__((ext_vector_type(16))) float f32x16;
typedef __attribute__((ext_vector_type(4))) unsigned u32x4;
typedef __attribute__((ext_vector_type(2))) int i32x2;

struct alignas(8) u16x4 { u16 x, y, z, w; };

#define MFMA16(A, B, C) __builtin_amdgcn_mfma_f32_16x16x32_bf16(A, B, C, 0, 0, 0)
#define MFMA32(A, B, C) __builtin_amdgcn_mfma_f32_32x32x16_bf16(A, B, C, 0, 0, 0)
// SCALE * log2(e): softmax computed in exp2 domain
#define QSCALE (0.17677669529663689f * 1.4426950408889634f)

__device__ __forceinline__ u16 f2bf(float f) {
  unsigned u = __float_as_uint(f);
  u = (u + 0x7fffu + ((u >> 16) & 1u)) >> 16;
  return (u16)u;
}

__device__ __forceinline__ bf16x8 ldb8(const u16* p) {
  return *reinterpret_cast<const bf16x8*>(p);
}

// async global->LDS, 16B per lane; LDS dest = uniform base + lane*16
__device__ __forceinline__ void glds16(const u16* g, u16* l) {
  __builtin_amdgcn_global_load_lds(
      (const __attribute__((address_space(1))) void*)g,
      (__attribute__((address_space(3))) void*)l, 16, 0, 0);
}

// ---------------------------------------------------------------- prep
__global__ __launch_bounds__(256) void prep_kernel(
    const float* __restrict__ x, const float* __restrict__ akv,
    const float* __restrict__ qw, const float* __restrict__ kvw,
    const float* __restrict__ Wq, const float* __restrict__ Wk,
    const float* __restrict__ Wv, const float* __restrict__ Wp,
    u16* __restrict__ xpT, u16* __restrict__ w2,
    u16* __restrict__ wqs, u16* __restrict__ wks,
    u16* __restrict__ wvs, u16* __restrict__ wps)
{
  __shared__ float sm[64 * 65];
  const int b = blockIdx.x, t = threadIdx.x;
  if (b < 512) {
    const int z = b >> 8, rem = b & 255;
    const int cib = (rem >> 6) * 64, y = rem & 63;
    const float* in = (z ? akv : x);
    const int tc = t & 63, tr = t >> 6;
    #pragma unroll
    for (int i = 0; i < 16; ++i) {
      const int ci = i * 4 + tr;
      sm[ci * 65 + tc] = in[(size_t)(cib + ci) * 4096 + y * 64 + tc];
    }
    __syncthreads();
    u16* dst = xpT + (size_t)z * 4356 * 256;
    #pragma unroll
    for (int i = 0; i < 16; ++i) {
      const int px = i * 4 + tr;
      dst[(size_t)((y + 1) * 66 + px + 1) * 256 + cib + tc] = f2bf(sm[tc * 65 + px]);
    }
    return;
  }
  if (b < 642) {
    const int slot = (b - 512) * 4 + (t >> 6);
    const int z = slot >= 260 ? 1 : 0;
    const int j = slot - z * 260;
    int pos;
    if (j < 66) pos = j;
    else if (j < 132) pos = 65 * 66 + (j - 66);
    else { const int j2 = j - 132; pos = (1 + (j2 >> 1)) * 66 + (j2 & 1) * 65; }
    u16x4 zr = {0, 0, 0, 0};
    *reinterpret_cast<u16x4*>(xpT + (size_t)z * 4356 * 256 + (size_t)pos * 256 + (t & 63) * 4) = zr;
    return;
  }
  if (b < 1154) {
    const int idx = b - 642;
    const int z = idx >> 8, co = idx & 255;
    const float* src = (z ? kvw : qw) + (size_t)co * 2304;
    u16* dst = w2 + (size_t)z * 256 * 2304 + (size_t)co * 2304;
    #pragma unroll
    for (int i = 0; i < 9; ++i) sm[i * 256 + t] = src[i * 256 + t];
    __syncthreads();
    #pragma unroll
    for (int i = 0; i < 9; ++i) dst[i * 256 + t] = f2bf(sm[t * 9 + i]);
    return;
  }
  {
    int idx = (b - 1154) * 256 + t;
    if (idx < 32768) { wqs[idx] = f2bf(Wq[idx] * QSCALE); return; }
    idx -= 32768;
    if (idx < 32768) { wks[idx] = f2bf(Wk[idx]); return; }
    idx -= 32768;
    if (idx < 65536) { wvs[idx] = f2bf(Wv[idx]); return; }
    idx -= 65536;
    wps[idx] = f2bf(Wp[idx]);
  }
}

// ---------------------------------------------------------------- conv3x3
// LDS-staged GEMM, triple-buffered with counted vmcnt(4) (T3/T4),
// T2 swizzle via pre-swizzled global source + swizzled ds_read.
__global__ __launch_bounds__(256, 2) void conv_kernel(
    const u16* __restrict__ xpT, const u16* __restrict__ w2,
    const float* __restrict__ qb, const float* __restrict__ kvb,
    u16* __restrict__ xqt, u16* __restrict__ kvt)
{
  __shared__ u16 ab[3][64 * 64];
  __shared__ u16 bb[3][64 * 64];

  const int z = blockIdx.z;
  const u16* __restrict__ X = xpT + (size_t)z * 4356 * 256;
  const u16* __restrict__ W = w2 + (size_t)z * 256 * 2304;
  const float* bias = z ? kvb : qb;
  u16* out = z ? kvt : xqt;

  const int lane = threadIdx.x & 63, w = threadIdx.x >> 6;
  const int lo = lane & 15, g = lane >> 4;
  const int r8 = lane >> 3, c = lane & 7;
  const int wr = w >> 1, wc = w & 1;
  const int cobase = blockIdx.x * 64;
  const int tbase = blockIdx.y * 64;

  const bool isA = (w < 2);
  const u16* gb[4];
  int ldso[4];
  #pragma unroll
  for (int q = 0; q < 4; ++q) {
    const int flat = w * 4 + q;
    if (flat < 8) {
      const int j = flat;
      gb[q] = W + (size_t)(cobase + j * 8 + r8) * 2304 + (c ^ r8) * 8;
      ldso[q] = j * 512;
    } else {
      const int j = flat - 8;
      const int tok = tbase + j * 8 + r8;
      const int padrow = ((tok >> 6) + 1) * 66 + (tok & 63) + 1;
      gb[q] = X + (size_t)padrow * 256 + (c ^ r8) * 8;
      ldso[q] = j * 512;
    }
  }

  f32x4 acc[2][2] = {};

  auto stage = [&](int s, int bsel) {
    int srcoff;
    if (isA) {
      srcoff = s * 64;
    } else {
      const int kk = s >> 2;
      const int koff = (kk / 3 - 1) * 66 + (kk % 3) - 1;
      srcoff = koff * 256 + (s & 3) * 64;
    }
    u16* lb = isA ? ab[bsel] : bb[bsel];
    #pragma unroll
    for (int q = 0; q < 4; ++q)
      glds16(gb[q] + srcoff, lb + ldso[q]);
  };

  stage(0, 0);
  stage(1, 1);
  asm volatile("s_waitcnt vmcnt(4)" ::: "memory");  // buf0 done; buf1 in flight
  __syncthreads();

  #pragma unroll 1
  for (int s = 0; s < 36; ++s) {
    const int cur = s % 3;
    if (s + 2 < 36) stage(s + 2, (s + 2) % 3);
    #pragma unroll
    for (int ks = 0; ks < 2; ++ks) {
      const int swz = ((ks * 4 + g) ^ (lo & 7)) * 8;
      const int rowA = wr * 32 + lo, colB = wc * 32 + lo;
      bf16x8 a0 = *reinterpret_cast<const bf16x8*>(&ab[cur][rowA * 64 + swz]);
      bf16x8 a1 = *reinterpret_cast<const bf16x8*>(&ab[cur][(rowA + 16) * 64 + swz]);
      bf16x8 b0 = *reinterpret_cast<const bf16x8*>(&bb[cur][colB * 64 + swz]);
      bf16x8 b1 = *reinterpret_cast<const bf16x8*>(&bb[cur][(colB + 16) * 64 + swz]);
      acc[0][0] = MFMA16(a0, b0, acc[0][0]);
      acc[0][1] = MFMA16(a0, b1, acc[0][1]);
      acc[1][0] = MFMA16(a1, b0, acc[1][0]);
      acc[1][1] = MFMA16(a1, b1, acc[1][1]);
    }
    if (s < 35) {
      if (s + 2 < 36) asm volatile("s_waitcnt vmcnt(4)" ::: "memory");
      else            asm volatile("s_waitcnt vmcnt(0)" ::: "memory");
      __syncthreads();
    }
  }

  #pragma unroll
  for (int af = 0; af < 2; ++af) {
    const int cb = cobase + wr * 32 + af * 16 + 4 * g;
    const float4 bi = *reinterpret_cast<const float4*>(bias + cb);
    #pragma unroll
    for (int bf = 0; bf < 2; ++bf) {
      const int t = tbase + wc * 32 + bf * 16 + lo;
      f32x4 v = acc[af][bf];
      u16x4 pk = { f2bf(v[0] + bi.x), f2bf(v[1] + bi.y),
                   f2bf(v[2] + bi.z), f2bf(v[3] + bi.w) };
      *reinterpret_cast<u16x4*>(out + (size_t)t * 256 + cb) = pk;
    }
  }
}

// ---------------------------------------------------------------- q/k/v proj (merged)
// grid (4, 64, 2): z=0 -> q (x<2) / k (x>=2), out [h][n][16];
//                  z=1 -> v, out in PRE-FRAGMENTED layout Vp.
// Depth-1 register prefetch on all fragment streams.
__global__ __launch_bounds__(256) void qkv_kernel(
    const u16* __restrict__ xqt, const u16* __restrict__ kvt,
    const u16* __restrict__ wqs, const u16* __restrict__ wks,
    const u16* __restrict__ wvs,
    const float* __restrict__ bq, const float* __restrict__ bk,
    const float* __restrict__ bv,
    u16* __restrict__ Qh, u16* __restrict__ Kh, u16* __restrict__ Vp)
{
  const int lane = threadIdx.x & 63, wid = threadIdx.x >> 6;
  const int lo = lane & 15, g = lane >> 4;
  const int bx = blockIdx.x;

  if (blockIdx.z == 0) {
    const bool isq = bx < 2;
    const u16* A = isq ? wqs : wks;
    const u16* Bm = isq ? xqt : kvt;
    const float* bias = isq ? bq : bk;
    const float bsc = isq ? (float)QSCALE : 1.f;
    u16* outp = isq ? Qh : Kh;
    const int c0 = (bx & 1) * 64 + (wid >> 1) * 32;
    const int n0 = blockIdx.y * 64 + (wid & 1) * 32;

    const u16* Ar0 = A + (c0 + lo) * 256 + 8 * g;
    const u16* Ar1 = A + (c0 + 16 + lo) * 256 + 8 * g;
    const u16* Br0 = Bm + (n0 + lo) * 256 + 8 * g;
    const u16* Br1 = Bm + (n0 + 16 + lo) * 256 + 8 * g;

    f32x4 acc[2][2] = {};
    bf16x8 A0 = ldb8(Ar0), A1 = ldb8(Ar1), B0 = ldb8(Br0), B1 = ldb8(Br1);
    #pragma unroll
    for (int s = 0; s < 8; ++s) {
      bf16x8 A0n, A1n, B0n, B1n;
      if (s < 7) {
        const int kn = (s + 1) * 32;
        A0n = ldb8(Ar0 + kn); A1n = ldb8(Ar1 + kn);
        B0n = ldb8(Br0 + kn); B1n = ldb8(Br1 + kn);
      }
      acc[0][0] = MFMA16(A0, B0, acc[0][0]);
      acc[0][1] = MFMA16(A0, B1, acc[0][1]);
      acc[1][0] = MFMA16(A1, B0, acc[1][0]);
      acc[1][1] = MFMA16(A1, B1, acc[1][1]);
      A0 = A0n; A1 = A1n; B0 = B0n; B1 = B1n;
    }
    #pragma unroll
    for (int af = 0; af < 2; ++af) {
      const int cb = c0 + af * 16 + 4 * g;
      const int h = cb >> 4, dd = cb & 15;
      const float4 bi = *reinterpret_cast<const float4*>(bias + cb);
      #pragma unroll
      for (int bfr = 0; bfr < 2; ++bfr) {
        const int n = n0 + bfr * 16 + lo;
        f32x4 v = acc[af][bfr];
        u16x4 pk = { f2bf(v[0] + bi.x * bsc), f2bf(v[1] + bi.y * bsc),
                     f2bf(v[2] + bi.z * bsc), f2bf(v[3] + bi.w * bsc) };
        *reinterpret_cast<u16x4*>(outp + h * 65536 + n * 16 + dd) = pk;
      }
    }
  } else {
    const int n0 = blockIdx.y * 64 + (wid >> 1) * 32;
    const int c0 = bx * 64 + (wid & 1) * 32;

    const u16* Ar0 = kvt + (n0 + lo) * 256 + 8 * g;
    const u16* Ar1 = kvt + (n0 + 16 + lo) * 256 + 8 * g;
    const u16* Br0 = wvs + (c0 + lo) * 256 + 8 * g;
    const u16* Br1 = wvs + (c0 + 16 + lo) * 256 + 8 * g;

    f32x4 acc[2][2] = {};
    bf16x8 A0 = ldb8(Ar0), A1 = ldb8(Ar1), B0 = ldb8(Br0), B1 = ldb8(Br1);
    #pragma unroll
    for (int s = 0; s < 8; ++s) {
      bf16x8 A0n, A1n, B0n, B1n;
      if (s < 7) {
        const int kn = (s + 1) * 32;
        A0n = ldb8(Ar0 + kn); A1n = ldb8(Ar1 + kn);
        B0n = ldb8(Br0 + kn); B1n = ldb8(Br1 + kn);
      }
      acc[0][0] = MFMA16(A0, B0, acc[0][0]);
      acc[0][1] = MFMA16(A0, B1, acc[0][1]);
      acc[1][0] = MFMA16(A1, B0, acc[1][0]);
      acc[1][1] = MFMA16(A1, B1, acc[1][1]);
      A0 = A0n; A1 = A1n; B0 = B0n; B1 = B1n;
    }
    #pragma unroll
    for (int af = 0; af < 2; ++af) {
      const int nb = n0 + af * 16 + 4 * g;
      const int tblk = nb >> 4, hhalf = (nb >> 3) & 1, j0 = nb & 7;
      #pragma unroll
      for (int bfr = 0; bfr < 2; ++bfr) {
        const int cc = c0 + bfr * 16 + lo;
        const int h = cc >> 5, dv = cc & 31;
        const float bi = bv[cc];
        f32x4 v = acc[af][bfr];
        u16x4 pk = { f2bf(v[0] + bi), f2bf(v[1] + bi),
                     f2bf(v[2] + bi), f2bf(v[3] + bi) };
        *reinterpret_cast<u16x4*>(
            Vp + (size_t)h * 131072 + tblk * 512 + hhalf * 256 + dv * 8 + j0) = pk;
      }
    }
  }
}

// ---------------------------------------------------------------- attention
// R11-verified config (69.55us, absmax 6.1e-5): 32x32 swapped-QK^T, no max
// tracking, 2 q-tiles/wave, head->XCD swizzle, depth-1 K/V register prefetch,
// #pragma unroll 2 on the kv loop. grid (512), block 512.
__global__ __launch_bounds__(512, 4) void attn_kernel(
    const u16* __restrict__ Qh, const u16* __restrict__ Kh,
    const u16* __restrict__ Vp, u16* __restrict__ O2)
{
  __shared__ float olds[16][8][64];
  __shared__ float l_ldsA[8][32], l_ldsB[8][32];
  __shared__ float invA[32], invB[32];

  const int lane = threadIdx.x & 63, w = threadIdx.x >> 6;  // w in [0,8)
  const int lo = lane & 31, hi = lane >> 5;
  const int bx = blockIdx.x;
  const int h = bx & 7, qg = bx >> 3;   // XCD i <- head i (round-robin dispatch)
  const int qt0 = qg * 64;

  const u16* Q = Qh + h * 65536;
  const u16* K = Kh + h * 65536;

  const bf16x8 qbA = ldb8(Q + (qt0 + lo) * 16 + 8 * hi);
  const bf16x8 qbB = ldb8(Q + (qt0 + 32 + lo) * 16 + 8 * hi);

  f32x16 oA = {0,0,0,0,0,0,0,0,0,0,0,0,0,0,0,0};
  f32x16 oB = {0,0,0,0,0,0,0,0,0,0,0,0,0,0,0,0};
  float lA0 = 0.f, lA1 = 0.f, lB0 = 0.f, lB1 = 0.f;
  const int kvbase = w * 512;

  const u16* kptr = K + (kvbase + lo) * 16 + 8 * hi;
  const u16* vptr = Vp + (size_t)h * 131072 + (size_t)kvbase * 32 + lane * 8;

  bf16x8 kb = ldb8(kptr);
  bf16x8 vb0 = ldb8(vptr);
  bf16x8 vb1 = ldb8(vptr + 512);

  #pragma unroll 2
  for (int st = 0; st < 16; ++st) {
    kptr += 512; vptr += 1024;
    // depth-1 prefetch (last iter reads spill into adjacent ws buffers: benign)
    const bf16x8 kb_n = ldb8(kptr);
    const bf16x8 vb0_n = ldb8(vptr);
    const bf16x8 vb1_n = ldb8(vptr + 512);

    const f32x16 zf = {0,0,0,0,0,0,0,0,0,0,0,0,0,0,0,0};
    f32x16 sA = MFMA32(kb, qbA, zf);
    f32x16 sB = MFMA32(kb, qbB, zf);

    // ---- tile A softmax+PV ----
    {
      unsigned cpk[8];
      #pragma unroll
      for (int r = 0; r < 16; r += 2) {
        const float p0 = __builtin_amdgcn_exp2f(sA[r]);
        const float p1 = __builtin_amdgcn_exp2f(sA[r + 1]);
        lA0 += p0; lA1 += p1;
        asm("v_cvt_pk_bf16_f32 %0, %1, %2" : "=v"(cpk[r >> 1]) : "v"(p0), "v"(p1));
      }
      u32x4 fa0, fa1;
      { i32x2 r2 = __builtin_amdgcn_permlane32_swap((int)cpk[0], (int)cpk[2], false, false);
        fa0[0] = (unsigned)r2[0]; fa0[2] = (unsigned)r2[1]; }
      { i32x2 r2 = __builtin_amdgcn_permlane32_swap((int)cpk[1], (int)cpk[3], false, false);
        fa0[1] = (unsigned)r2[0]; fa0[3] = (unsigned)r2[1]; }
      { i32x2 r2 = __builtin_amdgcn_permlane32_swap((int)cpk[4], (int)cpk[6], false, false);
        fa1[0] = (unsigned)r2[0]; fa1[2] = (unsigned)r2[1]; }
      { i32x2 r2 = __builtin_amdgcn_permlane32_swap((int)cpk[5], (int)cpk[7], false, false);
        fa1[1] = (unsigned)r2[0]; fa1[3] = (unsigned)r2[1]; }
      oA = MFMA32(__builtin_bit_cast(bf16x8, fa0), vb0, oA);
      oA = MFMA32(__builtin_bit_cast(bf16x8, fa1), vb1, oA);
    }
    // ---- tile B softmax+PV ----
    {
      unsigned cpk[8];
      #pragma unroll
      for (int r = 0; r < 16; r += 2) {
        const float p0 = __builtin_amdgcn_exp2f(sB[r]);
        const float p1 = __builtin_amdgcn_exp2f(sB[r + 1]);
        lB0 += p0; lB1 += p1;
        asm("v_cvt_pk_bf16_f32 %0, %1, %2" : "=v"(cpk[r >> 1]) : "v"(p0), "v"(p1));
      }
      u32x4 fa0, fa1;
      { i32x2 r2 = __builtin_amdgcn_permlane32_swap((int)cpk[0], (int)cpk[2], false, false);
        fa0[0] = (unsigned)r2[0]; fa0[2] = (unsigned)r2[1]; }
      { i32x2 r2 = __builtin_amdgcn_permlane32_swap((int)cpk[1], (int)cpk[3], false, false);
        fa0[1] = (unsigned)r2[0]; fa0[3] = (unsigned)r2[1]; }
      { i32x2 r2 = __builtin_amdgcn_permlane32_swap((int)cpk[4], (int)cpk[6], false, false);
        fa1[0] = (unsigned)r2[0]; fa1[2] = (unsigned)r2[1]; }
      { i32x2 r2 = __builtin_amdgcn_permlane32_swap((int)cpk[5], (int)cpk[7], false, false);
        fa1[1] = (unsigned)r2[0]; fa1[3] = (unsigned)r2[1]; }
      oB = MFMA32(__builtin_bit_cast(bf16x8, fa0), vb0, oB);
      oB = MFMA32(__builtin_bit_cast(bf16x8, fa1), vb1, oB);
    }
    kb = kb_n; vb0 = vb0_n; vb1 = vb1_n;
  }

  // ---- cross-wave combine, two passes over one olds buffer ----
  float lA = lA0 + lA1;  lA += __shfl_xor(lA, 32);
  float lB = lB0 + lB1;  lB += __shfl_xor(lB, 32);
  if (lane < 32) { l_ldsA[w][lane] = lA; l_ldsB[w][lane] = lB; }

  #pragma unroll
  for (int r = 0; r < 16; ++r) olds[r][w][lane] = oA[r];
  __syncthreads();

  if (w == 0 && lane < 32) {
    float L = 0.f;
    #pragma unroll
    for (int w2 = 0; w2 < 8; ++w2) L += l_ldsA[w2][lane];
    invA[lane] = 1.0f / L;
  }
  if (w == 1 && lane < 32) {
    float L = 0.f;
    #pragma unroll
    for (int w2 = 0; w2 < 8; ++w2) L += l_ldsB[w2][lane];
    invB[lane] = 1.0f / L;
  }
  __syncthreads();

  #pragma unroll
  for (int j = 0; j < 2; ++j) {
    const int r = 2 * w + j;
    const int q = (r & 3) + 8 * (r >> 2) + 4 * hi;
    float acc = 0.f;
    #pragma unroll
    for (int w2 = 0; w2 < 8; ++w2) acc += olds[r][w2][lane];
    acc *= invA[q];
    const int n = qt0 + q;
    O2[(size_t)((h << 9) + (n >> 3)) * 256 + ((n & 7) << 5) + lo] = f2bf(acc);
  }
  __syncthreads();

  #pragma unroll
  for (int r = 0; r < 16; ++r) olds[r][w][lane] = oB[r];
  __syncthreads();

  #pragma unroll
  for (int j = 0; j < 2; ++j) {
    const int r = 2 * w + j;
    const int q = (r & 3) + 8 * (r >> 2) + 4 * hi;
    float acc = 0.f;
    #pragma unroll
    for (int w2 = 0; w2 < 8; ++w2) acc += olds[r][w2][lane];
    acc *= invB[q];
    const int n = qt0 + 32 + q;
    O2[(size_t)((h << 9) + (n >> 3)) * 256 + ((n & 7) << 5) + lo] = f2bf(acc);
  }
}

// ---------------------------------------------------------------- out proj
// R7-verified: 64n x 64c tile, 2x2 acc/wave, grid (64,4).
__global__ __launch_bounds__(256) void oproj_kernel(
    const u16* __restrict__ O2, const u16* __restrict__ wps,
    const float* __restrict__ bp, float* __restrict__ outp)
{
  const int lane = threadIdx.x & 63, wid = threadIdx.x >> 6;
  const int lo = lane & 15, g = lane >> 4;
  const int n0 = blockIdx.x * 64 + (wid >> 1) * 32;
  const int c0 = blockIdx.y * 64 + (wid & 1) * 32;

  f32x4 acc[2][2] = {};
  #pragma unroll
  for (int s = 0; s < 8; ++s) {
    const int k0 = s * 32 + 8 * g;
    bf16x8 A0 = ldb8(O2 + (n0 + lo) * 256 + k0);
    bf16x8 A1 = ldb8(O2 + (n0 + 16 + lo) * 256 + k0);
    bf16x8 B0 = ldb8(wps + (c0 + lo) * 256 + k0);
    bf16x8 B1 = ldb8(wps + (c0 + 16 + lo) * 256 + k0);
    acc[0][0] = MFMA16(A0, B0, acc[0][0]);
    acc[0][1] = MFMA16(A0, B1, acc[0][1]);
    acc[1][0] = MFMA16(A1, B0, acc[1][0]);
    acc[1][1] = MFMA16(A1, B1, acc[1][1]);
  }
  #pragma unroll
  for (int af = 0; af < 2; ++af) {
    const int nb = n0 + af * 16 + 4 * g;
    #pragma unroll
    for (int bfr = 0; bfr < 2; ++bfr) {
      const int c = c0 + bfr * 16 + lo;
      const float bi = bp[c];
      f32x4 v = acc[af][bfr];
      float4 r4;
      r4.x = v[0] + bi; r4.y = v[1] + bi; r4.z = v[2] + bi; r4.w = v[3] + bi;
      *reinterpret_cast<float4*>(outp + (size_t)c * 4096 + nb) = r4;
    }
  }
}

// ---------------------------------------------------------------- launch
extern "C" void kernel_launch(void* const* d_in, const int* in_sizes, int n_in,
                              void* d_out, int out_size, void* d_ws, size_t ws_size,
                              hipStream_t stream) {
  (void)in_sizes; (void)n_in; (void)out_size; (void)ws_size;
  const float* x   = (const float*)d_in[0];
  const float* akv = (const float*)d_in[1];
  const float* qw  = (const float*)d_in[2];
  const float* qb  = (const float*)d_in[3];
  const float* kvw = (const float*)d_in[4];
  const float* kvb = (const float*)d_in[5];
  const float* Wq  = (const float*)d_in[6];
  const float* bq  = (const float*)d_in[7];
  const float* Wk  = (const float*)d_in[8];
  const float* bk  = (const float*)d_in[9];
  const float* Wv  = (const float*)d_in[10];
  const float* bv  = (const float*)d_in[11];
  const float* Wp  = (const float*)d_in[12];
  const float* bp  = (const float*)d_in[13];
  float* outp = (float*)d_out;

  char* wsb = (char*)d_ws;
  size_t off = 0;
  auto take = [&](size_t bytes) {
    char* p = wsb + off;
    off = (off + bytes + 255) & ~(size_t)255;
    return p;
  };
  u16* xpT = (u16*)take(2ULL * 4356 * 256 * 2);
  u16* w2  = (u16*)take(2ULL * 256 * 2304 * 2);
  u16* wqs = (u16*)take(128ULL * 256 * 2);
  u16* wks = (u16*)take(128ULL * 256 * 2);
  u16* wvs = (u16*)take(256ULL * 256 * 2);
  u16* wps = (u16*)take(256ULL * 256 * 2);
  u16* xqt = (u16*)take(4096ULL * 256 * 2);
  u16* kvt = (u16*)take(4096ULL * 256 * 2);
  u16* Qh  = (u16*)take(8ULL * 4096 * 16 * 2);
  u16* Kh  = (u16*)take(8ULL * 4096 * 16 * 2);
  u16* Vp  = (u16*)take(8ULL * 131072 * 2);
  u16* O2  = (u16*)take(4096ULL * 256 * 2);

  prep_kernel<<<dim3(1922), dim3(256), 0, stream>>>(
      x, akv, qw, kvw, Wq, Wk, Wv, Wp, xpT, w2, wqs, wks, wvs, wps);
  conv_kernel<<<dim3(4, 64, 2), dim3(256), 0, stream>>>(xpT, w2, qb, kvb, xqt, kvt);
  qkv_kernel<<<dim3(4, 64, 2), dim3(256), 0, stream>>>(
      xqt, kvt, wqs, wks, wvs, bq, bk, bv, Qh, Kh, Vp);
  attn_kernel<<<dim3(512), dim3(512), 0, stream>>>(Qh, Kh, Vp, O2);
  oproj_kernel<<<dim3(64, 4), dim3(256), 0, stream>>>(O2, wps, bp, outp);
}